// Round 2
// baseline (514.870 us; speedup 1.0000x reference)
//
#include <hip/hip_runtime.h>
#include <math.h>

#define TOKENS 16384
#define DD 4096
#define NE 64
#define MBLK 256      // tokens per k1 block (= blockDim)

// ---- k0: transpose W[e][k] -> WT[k][e] (1 MB, once per launch) ----
__global__ void k0_transpose(const float* __restrict__ Wg, float* __restrict__ WT) {
  const int k0 = blockIdx.x * 64;
  const int e  = threadIdx.x & 63;
  const int kq = threadIdx.x >> 6;          // 0..3
#pragma unroll
  for (int kk = 0; kk < 16; ++kk) {
    const int k = k0 + kq * 16 + kk;
    WT[(long)k * NE + e] = Wg[(long)e * DD + k];
  }
}

// ---- k1: partial GEMM, lane=token, acc over all 64 experts ----
// W row per kk is block-uniform -> s_load into SGPRs; x streams per-lane.
__global__ __launch_bounds__(256, 2)
void k1_gemm(const float* __restrict__ x, const float* __restrict__ WT,
             float* __restrict__ part, int kPerSlice) {
  const int nm   = TOKENS / MBLK;           // 64
  const int mblk = blockIdx.x % nm;
  const int s    = blockIdx.x / nm;
  const int tid  = threadIdx.x;
  const long t   = (long)mblk * MBLK + tid; // this lane's token
  const int k0   = s * kPerSlice;

  const float* xp = x + t * (long)DD + k0;  // per-lane contiguous k-stream
  const float* wk = WT + (long)k0 * NE;     // block-uniform

  float acc[NE];
#pragma unroll
  for (int e = 0; e < NE; ++e) acc[e] = 0.f;

  float4 a = *(const float4*)(xp);
  float4 b = *(const float4*)(xp + 4);

  for (int kb = 0; kb < kPerSlice; kb += 8) {
    float4 an, bn;
    const bool more = (kb + 8 < kPerSlice);
    if (more) {
      an = *(const float4*)(xp + kb + 8);
      bn = *(const float4*)(xp + kb + 12);
    }
    const float* w8 = wk + (long)kb * NE;
#pragma unroll
    for (int kq = 0; kq < 8; ++kq) {
      const float xvk = (kq < 4) ? (&a.x)[kq] : (&b.x)[kq - 4];
      const float* wrow = w8 + kq * NE;     // uniform -> s_load_dwordx16
#pragma unroll
      for (int e = 0; e < NE; ++e) acc[e] += wrow[e] * xvk;
    }
    if (more) { a = an; b = bn; }
  }

  // partials: contiguous 256 B per lane
  float* pb = part + ((long)s * TOKENS + t) * NE;
#pragma unroll
  for (int q = 0; q < 16; ++q)
    *(float4*)(pb + 4 * q) =
        make_float4(acc[4*q], acc[4*q+1], acc[4*q+2], acc[4*q+3]);
}

// ---- k2: reduce partials + softmax + top-2 + outputs ----
__global__ __launch_bounds__(256)
void k2_finish(const float* __restrict__ part, int S, float* __restrict__ out) {
  const int tid  = threadIdx.x;
  const int lane = tid & 63;
  const int wv   = tid >> 6;
  const long t   = (long)blockIdx.x * 4 + wv;

  const float* p = part + t * NE + lane;
  float logit = 0.f;
  for (int s = 0; s < S; ++s) logit += p[(long)s * TOKENS * NE];

  out[4 * TOKENS + t * NE + lane] = logit;  // logits region

  // argmax (tie -> lowest index, matches jax.lax.top_k)
  float v = logit; int i = lane;
#pragma unroll
  for (int off = 32; off; off >>= 1) {
    float ov = __shfl_xor(v, off);
    int   oi = __shfl_xor(i, off);
    if (ov > v || (ov == v && oi < i)) { v = ov; i = oi; }
  }
  const float m = v; const int i1 = i;

  float vv = (lane == i1) ? -INFINITY : logit; int ii = lane;
#pragma unroll
  for (int off = 32; off; off >>= 1) {
    float ov = __shfl_xor(vv, off);
    int   oi = __shfl_xor(ii, off);
    if (ov > vv || (ov == vv && oi < ii)) { vv = ov; ii = oi; }
  }
  const int i2 = ii;

  float z = expf(logit - m);
  float Z = z;
#pragma unroll
  for (int off = 32; off; off >>= 1) Z += __shfl_xor(Z, off);

  float p1 = __shfl(z, i1) / Z;
  float p2 = __shfl(z, i2) / Z;

  if (lane == 0) {
    float denom = p1 + p2 + 1e-9f;
    out[t * 2 + 0] = (float)i1;               // indices [0, 2T)
    out[t * 2 + 1] = (float)i2;
    out[2 * TOKENS + t * 2 + 0] = p1 / denom; // weights [2T, 4T)
    out[2 * TOKENS + t * 2 + 1] = p2 / denom;
  }
}

extern "C" void kernel_launch(void* const* d_in, const int* in_sizes, int n_in,
                              void* d_out, int out_size, void* d_ws, size_t ws_size,
                              hipStream_t stream) {
  const float* x  = (const float*)d_in[0];
  const float* Wg = (const float*)d_in[1];
  float* out = (float*)d_out;

  float* WT = (float*)d_ws;
  const size_t wtBytes    = (size_t)DD * NE * sizeof(float);      // 1 MB
  const size_t sliceBytes = (size_t)TOKENS * NE * sizeof(float);  // 4.19 MB

  int S = 8;
  while (S > 1 && wtBytes + (size_t)S * sliceBytes > ws_size) S >>= 1;
  float* part = (float*)((char*)d_ws + wtBytes);
  if (wtBytes + sliceBytes > ws_size) {      // degenerate tiny-ws fallback
    S = 1;
    part = out + 4 * TOKENS;                 // logits region doubles as partials
  }
  const int kPerSlice = DD / S;

  k0_transpose<<<dim3(DD / 64), 256, 0, stream>>>(Wg, WT);
  k1_gemm<<<dim3((TOKENS / MBLK) * S), 256, 0, stream>>>(x, WT, part, kPerSlice);
  k2_finish<<<dim3(TOKENS / 4), 256, 0, stream>>>(part, S, out);
}